// Round 1
// baseline (86.618 us; speedup 1.0000x reference)
//
#include <hip/hip_runtime.h>
#include <math.h>

#define BB 4096
#define DD 1024
#define KK 5
#define PP 1323
#define PTS_PER_THREAD 21   // 1323 = 63 * 21

// (2*pi)^(-3/2)
#define INV_2PI_POW15 0.06349363593424097f

__device__ __forceinline__ float softplus_f(float x) {
    return (x > 20.f) ? x : log1pf(expf(x));
}

// Kernel 1: per-batch head. One wave (64 threads) per batch row.
// Computes logits/means/scales GEMV (47 outputs), softmax, Cholesky prep.
// Writes L [B,K,3,3] to Lout and SoA params [50][B] to par.
__global__ __launch_bounds__(64) void head_kernel(
    const float* __restrict__ rep,
    const float* __restrict__ Wmix,  const float* __restrict__ bmix,
    const float* __restrict__ Wmean, const float* __restrict__ bmean,
    const float* __restrict__ Wscale,const float* __restrict__ bscale,
    float* __restrict__ Lout,
    float* __restrict__ par)
{
    const int b    = blockIdx.x;
    const int lane = threadIdx.x;

    float acc[47];
#pragma unroll
    for (int j = 0; j < 47; ++j) acc[j] = 0.f;

    const float* rrow = rep + (size_t)b * DD;

    for (int d = lane; d < DD; d += 64) {
        const float x = rrow[d];
        const float* wm  = Wmix  + d * 5;
#pragma unroll
        for (int j = 0; j < 5; ++j)  acc[j]      = fmaf(x, wm[j],  acc[j]);
        const float* wmn = Wmean + d * 12;
#pragma unroll
        for (int j = 0; j < 12; ++j) acc[5 + j]  = fmaf(x, wmn[j], acc[5 + j]);
        const float* wsc = Wscale + d * 30;
#pragma unroll
        for (int j = 0; j < 30; ++j) acc[17 + j] = fmaf(x, wsc[j], acc[17 + j]);
    }

    // 64-lane butterfly reduction of all 47 accumulators
#pragma unroll
    for (int off = 32; off > 0; off >>= 1) {
#pragma unroll
        for (int j = 0; j < 47; ++j)
            acc[j] += __shfl_xor(acc[j], off, 64);
    }

    if (lane == 0) {
        // softmax over 5 logits
        float logits[KK];
#pragma unroll
        for (int k = 0; k < KK; ++k) logits[k] = acc[k] + bmix[k];
        float mx = logits[0];
#pragma unroll
        for (int k = 1; k < KK; ++k) mx = fmaxf(mx, logits[k]);
        float e[KK]; float s = 0.f;
#pragma unroll
        for (int k = 0; k < KK; ++k) { e[k] = expf(logits[k] - mx); s += e[k]; }
        const float inv_s = 1.f / s;

        float means[12];
#pragma unroll
        for (int j = 0; j < 12; ++j) means[j] = acc[5 + j] + bmean[j];

#pragma unroll
        for (int k = 0; k < KK; ++k) {
            const float s0 = acc[17 + k * 6 + 0] + bscale[k * 6 + 0];
            const float s1 = acc[17 + k * 6 + 1] + bscale[k * 6 + 1];
            const float s2 = acc[17 + k * 6 + 2] + bscale[k * 6 + 2];
            const float s3 = acc[17 + k * 6 + 3] + bscale[k * 6 + 3];
            const float s4 = acc[17 + k * 6 + 4] + bscale[k * 6 + 4];
            const float s5 = acc[17 + k * 6 + 5] + bscale[k * 6 + 5];

            const float L00 = softplus_f(s0);
            const float L10 = s1;
            const float L11 = softplus_f(s2);
            const float L20 = s3;
            const float L21 = s4;
            const float L22 = softplus_f(s5);

            const float m0 = (k == 0) ? 0.f : means[(k - 1) * 3 + 0];
            const float m1 = (k == 0) ? 0.f : means[(k - 1) * 3 + 1];
            const float m2 = (k == 0) ? 0.f : means[(k - 1) * 3 + 2];

            const float r00 = 1.f / L00;
            const float r11 = 1.f / L11;
            const float r22 = 1.f / L22;
            const float w   = e[k] * inv_s;
            const float a   = w * r00 * r11 * r22 * INV_2PI_POW15;

            // L output: [B, K, 3, 3]
            float* Lo = Lout + ((size_t)b * KK + k) * 9;
            Lo[0] = L00; Lo[1] = 0.f; Lo[2] = 0.f;
            Lo[3] = L10; Lo[4] = L11; Lo[5] = 0.f;
            Lo[6] = L20; Lo[7] = L21; Lo[8] = L22;

            // SoA params: par[j*B + b], j = k*10 + {0..9}
            const int pj = k * 10;
            par[(pj + 0) * BB + b] = m0;
            par[(pj + 1) * BB + b] = m1;
            par[(pj + 2) * BB + b] = m2;
            par[(pj + 3) * BB + b] = r00;
            par[(pj + 4) * BB + b] = L10;
            par[(pj + 5) * BB + b] = r11;
            par[(pj + 6) * BB + b] = L20;
            par[(pj + 7) * BB + b] = L21;
            par[(pj + 8) * BB + b] = r22;
            par[(pj + 9) * BB + b] = a;
        }
    }
}

// Kernel 2: per-(p,b) mixture density. Thread owns one b, 21 points.
// out[p*B + b] = sum_k a_k * exp(-0.5 * |L^-1 (x - mu)|^2)
__global__ __launch_bounds__(256) void eval_kernel(
    const float* __restrict__ dxyz,
    const float* __restrict__ par,
    float* __restrict__ out)
{
    const int b = blockIdx.x * 256 + threadIdx.x;

    float m0[KK], m1[KK], m2[KK], r00[KK], l10[KK], r11[KK], l20[KK], l21[KK], r22[KK], am[KK];
#pragma unroll
    for (int k = 0; k < KK; ++k) {
        const int pj = k * 10;
        m0[k]  = par[(pj + 0) * BB + b];
        m1[k]  = par[(pj + 1) * BB + b];
        m2[k]  = par[(pj + 2) * BB + b];
        r00[k] = par[(pj + 3) * BB + b];
        l10[k] = par[(pj + 4) * BB + b];
        r11[k] = par[(pj + 5) * BB + b];
        l20[k] = par[(pj + 6) * BB + b];
        l21[k] = par[(pj + 7) * BB + b];
        r22[k] = par[(pj + 8) * BB + b];
        am[k]  = par[(pj + 9) * BB + b];
    }

    const int p0 = blockIdx.y * PTS_PER_THREAD;
#pragma unroll 3
    for (int i = 0; i < PTS_PER_THREAD; ++i) {
        const int p = p0 + i;
        const size_t idx = (size_t)p * BB + b;
        const float* xv = dxyz + idx * 3;
        const float x0 = xv[0];
        const float x1 = xv[1];
        const float x2 = xv[2];

        float res = 0.f;
#pragma unroll
        for (int k = 0; k < KK; ++k) {
            const float d0 = x0 - m0[k];
            const float d1 = x1 - m1[k];
            const float d2 = x2 - m2[k];
            const float z0 = d0 * r00[k];
            const float z1 = fmaf(-l10[k], z0, d1) * r11[k];
            const float z2 = fmaf(-l21[k], z1, fmaf(-l20[k], z0, d2)) * r22[k];
            const float q  = fmaf(z2, z2, fmaf(z1, z1, z0 * z0));
            res = fmaf(am[k], __expf(-0.5f * q), res);
        }
        out[idx] = res;
    }
}

extern "C" void kernel_launch(void* const* d_in, const int* in_sizes, int n_in,
                              void* d_out, int out_size, void* d_ws, size_t ws_size,
                              hipStream_t stream) {
    const float* rep    = (const float*)d_in[0];
    const float* dxyz   = (const float*)d_in[1];
    const float* Wmix   = (const float*)d_in[2];
    const float* bmix   = (const float*)d_in[3];
    const float* Wmean  = (const float*)d_in[4];
    const float* bmean  = (const float*)d_in[5];
    const float* Wscale = (const float*)d_in[6];
    const float* bscale = (const float*)d_in[7];

    float* out  = (float*)d_out;
    float* Lout = out + (size_t)BB * PP;   // second tuple output
    float* par  = (float*)d_ws;            // 50 * B floats = 819 KB

    head_kernel<<<BB, 64, 0, stream>>>(rep, Wmix, bmix, Wmean, bmean,
                                       Wscale, bscale, Lout, par);

    eval_kernel<<<dim3(BB / 256, PP / PTS_PER_THREAD), 256, 0, stream>>>(dxyz, par, out);
}

// Round 2
// 66.473 us; speedup vs baseline: 1.3031x; 1.3031x over previous
//
#include <hip/hip_runtime.h>
#include <math.h>

#define BB 4096
#define DD 1024
#define KK 5
#define PP 1323
#define PTS_PER_THREAD 21   // 1323 = 63 * 21

// (2*pi)^(-3/2)
#define INV_2PI_POW15 0.06349363593424097f

// ---- head GEMM config ----
#define RPB 64        // rows per block
#define KSPL 4        // cross-block K splits (grid.y)
#define KRANGE 256    // K per block = DD / KSPL
#define KQ 4          // in-block K quarters (one per wave)
#define KTH 64        // K per thread = KRANGE / KQ
#define NC 48         // padded output cols (47 real)
#define REP_STRIDE 260 // 256 + 4 pad -> 8-way bank spread on b128 column reads
#define RED_STRIDE 52  // 48 + 4 pad for reduction tile

__device__ __forceinline__ float softplus_f(float x) {
    return (x > 20.f) ? x : log1pf(expf(x));
}

// ---------------------------------------------------------------------------
// Kernel 1: head GEMM. out_part[kz][j][b] = sum_{d in kz-range} rep[b][d]*W[d][j]
// 256 blocks (64 row-tiles x 4 k-splits), 256 threads.
// Thread = one row x one k-quarter, owns all 48 column accumulators.
// Weight reads are wave-uniform LDS broadcasts; rep scalar from registers.
// ---------------------------------------------------------------------------
__global__ __launch_bounds__(256) void gemm_kernel(
    const float* __restrict__ rep,
    const float* __restrict__ Wmix,
    const float* __restrict__ Wmean,
    const float* __restrict__ Wscale,
    float* __restrict__ ws_part)
{
    __shared__ float s_rep[RPB * REP_STRIDE];   // 64 x 260 = 66.6 KB
    __shared__ float s_w[KRANGE * NC];          // 256 x 48 = 49.2 KB

    const int t  = threadIdx.x;
    const int b0 = blockIdx.x * RPB;
    const int k0 = blockIdx.y * KRANGE;

    // ---- stage rep tile [64 rows][256 k] (fully coalesced float4) ----
#pragma unroll
    for (int i = 0; i < 16; ++i) {
        const int s   = i * 256 + t;
        const int row = s >> 6;        // 64 float4 per row
        const int c4  = s & 63;
        const float4 v = *(const float4*)(rep + (size_t)(b0 + row) * DD + k0 + c4 * 4);
        *(float4*)(s_rep + row * REP_STRIDE + c4 * 4) = v;
    }

    // ---- stage packed weights [256 k][48 j] (j-fast for coalesced reads) ----
#pragma unroll
    for (int i = 0; i < 48; ++i) {
        const int lin = i * 256 + t;           // 0..12287
        const int j   = lin % NC;
        const int kk  = lin / NC;
        const int d   = k0 + kk;
        float v;
        if (j < 5)       v = Wmix[d * 5 + j];
        else if (j < 17) v = Wmean[d * 12 + (j - 5)];
        else if (j < 47) v = Wscale[d * 30 + (j - 17)];
        else             v = 0.f;
        s_w[kk * NC + j] = v;
    }
    __syncthreads();

    const int row = t & 63;
    const int kq  = t >> 6;   // wave id: all lanes in a wave share kq -> broadcast w reads

    float acc[NC];
#pragma unroll
    for (int j = 0; j < NC; ++j) acc[j] = 0.f;

    const float* rbase = s_rep + row * REP_STRIDE + kq * KTH;
    const float* wbase = s_w + kq * KTH * NC;

#pragma unroll 4
    for (int g = 0; g < KTH / 4; ++g) {
        const float4 rv = *(const float4*)(rbase + g * 4);
        const float rs[4] = { rv.x, rv.y, rv.z, rv.w };
#pragma unroll
        for (int u = 0; u < 4; ++u) {
            const float r = rs[u];
            const float* wrow = wbase + (g * 4 + u) * NC;
#pragma unroll
            for (int j4 = 0; j4 < NC / 4; ++j4) {
                const float4 wv = *(const float4*)(wrow + j4 * 4);
                acc[j4 * 4 + 0] = fmaf(r, wv.x, acc[j4 * 4 + 0]);
                acc[j4 * 4 + 1] = fmaf(r, wv.y, acc[j4 * 4 + 1]);
                acc[j4 * 4 + 2] = fmaf(r, wv.z, acc[j4 * 4 + 2]);
                acc[j4 * 4 + 3] = fmaf(r, wv.w, acc[j4 * 4 + 3]);
            }
        }
    }

    // ---- in-block reduction over the 4 k-quarters (reuse s_rep area) ----
    __syncthreads();                 // all s_rep reads done before overwrite
    float* red = s_rep;              // [3][64][RED_STRIDE] = 9984 floats < 16640
    if (kq > 0) {
        float* dst = red + ((kq - 1) * 64 + row) * RED_STRIDE;
#pragma unroll
        for (int j4 = 0; j4 < NC / 4; ++j4) {
            float4 v = { acc[j4 * 4 + 0], acc[j4 * 4 + 1], acc[j4 * 4 + 2], acc[j4 * 4 + 3] };
            *(float4*)(dst + j4 * 4) = v;
        }
    }
    __syncthreads();
    if (kq == 0) {
#pragma unroll
        for (int q = 0; q < 3; ++q) {
            const float* src = red + (q * 64 + row) * RED_STRIDE;
#pragma unroll
            for (int j4 = 0; j4 < NC / 4; ++j4) {
                const float4 v = *(const float4*)(src + j4 * 4);
                acc[j4 * 4 + 0] += v.x;
                acc[j4 * 4 + 1] += v.y;
                acc[j4 * 4 + 2] += v.z;
                acc[j4 * 4 + 3] += v.w;
            }
        }
        // partials: ws_part[(kz*NC + j)*BB + b]  (coalesced: row = lane)
        const size_t base = (size_t)blockIdx.y * NC * BB + b0 + row;
#pragma unroll
        for (int j = 0; j < 47; ++j)
            ws_part[base + (size_t)j * BB] = acc[j];
    }
}

// ---------------------------------------------------------------------------
// Kernel 2: epilogue. One thread per batch row: sum k-split partials, add
// biases, softmax, softplus Cholesky, write L and SoA params.
// ---------------------------------------------------------------------------
__global__ __launch_bounds__(256) void epilogue_kernel(
    const float* __restrict__ ws_part,
    const float* __restrict__ bmix,
    const float* __restrict__ bmean,
    const float* __restrict__ bscale,
    float* __restrict__ Lout,
    float* __restrict__ par)
{
    const int b = blockIdx.x * 256 + threadIdx.x;

    float v[47];
#pragma unroll
    for (int j = 0; j < 47; ++j) {
        float s = 0.f;
#pragma unroll
        for (int kz = 0; kz < KSPL; ++kz)
            s += ws_part[((size_t)kz * NC + j) * BB + b];
        v[j] = s;
    }

    // softmax over 5 logits
    float logits[KK];
#pragma unroll
    for (int k = 0; k < KK; ++k) logits[k] = v[k] + bmix[k];
    float mx = logits[0];
#pragma unroll
    for (int k = 1; k < KK; ++k) mx = fmaxf(mx, logits[k]);
    float e[KK]; float s = 0.f;
#pragma unroll
    for (int k = 0; k < KK; ++k) { e[k] = expf(logits[k] - mx); s += e[k]; }
    const float inv_s = 1.f / s;

    float means[12];
#pragma unroll
    for (int j = 0; j < 12; ++j) means[j] = v[5 + j] + bmean[j];

#pragma unroll
    for (int k = 0; k < KK; ++k) {
        const float s0 = v[17 + k * 6 + 0] + bscale[k * 6 + 0];
        const float s1 = v[17 + k * 6 + 1] + bscale[k * 6 + 1];
        const float s2 = v[17 + k * 6 + 2] + bscale[k * 6 + 2];
        const float s3 = v[17 + k * 6 + 3] + bscale[k * 6 + 3];
        const float s4 = v[17 + k * 6 + 4] + bscale[k * 6 + 4];
        const float s5 = v[17 + k * 6 + 5] + bscale[k * 6 + 5];

        const float L00 = softplus_f(s0);
        const float L10 = s1;
        const float L11 = softplus_f(s2);
        const float L20 = s3;
        const float L21 = s4;
        const float L22 = softplus_f(s5);

        const float m0 = (k == 0) ? 0.f : means[(k - 1) * 3 + 0];
        const float m1 = (k == 0) ? 0.f : means[(k - 1) * 3 + 1];
        const float m2 = (k == 0) ? 0.f : means[(k - 1) * 3 + 2];

        const float r00 = 1.f / L00;
        const float r11 = 1.f / L11;
        const float r22 = 1.f / L22;
        const float w   = e[k] * inv_s;
        const float a   = w * r00 * r11 * r22 * INV_2PI_POW15;

        float* Lo = Lout + ((size_t)b * KK + k) * 9;
        Lo[0] = L00; Lo[1] = 0.f; Lo[2] = 0.f;
        Lo[3] = L10; Lo[4] = L11; Lo[5] = 0.f;
        Lo[6] = L20; Lo[7] = L21; Lo[8] = L22;

        const int pj = k * 10;
        par[(pj + 0) * BB + b] = m0;
        par[(pj + 1) * BB + b] = m1;
        par[(pj + 2) * BB + b] = m2;
        par[(pj + 3) * BB + b] = r00;
        par[(pj + 4) * BB + b] = L10;
        par[(pj + 5) * BB + b] = r11;
        par[(pj + 6) * BB + b] = L20;
        par[(pj + 7) * BB + b] = L21;
        par[(pj + 8) * BB + b] = r22;
        par[(pj + 9) * BB + b] = a;
    }
}

// ---------------------------------------------------------------------------
// Kernel 3: per-(p,b) mixture density (memory-bound, at HBM floor).
// out[p*B + b] = sum_k a_k * exp(-0.5 * |L^-1 (x - mu)|^2)
// ---------------------------------------------------------------------------
__global__ __launch_bounds__(256) void eval_kernel(
    const float* __restrict__ dxyz,
    const float* __restrict__ par,
    float* __restrict__ out)
{
    const int b = blockIdx.x * 256 + threadIdx.x;

    float m0[KK], m1[KK], m2[KK], r00[KK], l10[KK], r11[KK], l20[KK], l21[KK], r22[KK], am[KK];
#pragma unroll
    for (int k = 0; k < KK; ++k) {
        const int pj = k * 10;
        m0[k]  = par[(pj + 0) * BB + b];
        m1[k]  = par[(pj + 1) * BB + b];
        m2[k]  = par[(pj + 2) * BB + b];
        r00[k] = par[(pj + 3) * BB + b];
        l10[k] = par[(pj + 4) * BB + b];
        r11[k] = par[(pj + 5) * BB + b];
        l20[k] = par[(pj + 6) * BB + b];
        l21[k] = par[(pj + 7) * BB + b];
        r22[k] = par[(pj + 8) * BB + b];
        am[k]  = par[(pj + 9) * BB + b];
    }

    const int p0 = blockIdx.y * PTS_PER_THREAD;
#pragma unroll 3
    for (int i = 0; i < PTS_PER_THREAD; ++i) {
        const int p = p0 + i;
        const size_t idx = (size_t)p * BB + b;
        const float* xv = dxyz + idx * 3;
        const float x0 = xv[0];
        const float x1 = xv[1];
        const float x2 = xv[2];

        float res = 0.f;
#pragma unroll
        for (int k = 0; k < KK; ++k) {
            const float d0 = x0 - m0[k];
            const float d1 = x1 - m1[k];
            const float d2 = x2 - m2[k];
            const float z0 = d0 * r00[k];
            const float z1 = fmaf(-l10[k], z0, d1) * r11[k];
            const float z2 = fmaf(-l21[k], z1, fmaf(-l20[k], z0, d2)) * r22[k];
            const float q  = fmaf(z2, z2, fmaf(z1, z1, z0 * z0));
            res = fmaf(am[k], __expf(-0.5f * q), res);
        }
        out[idx] = res;
    }
}

extern "C" void kernel_launch(void* const* d_in, const int* in_sizes, int n_in,
                              void* d_out, int out_size, void* d_ws, size_t ws_size,
                              hipStream_t stream) {
    const float* rep    = (const float*)d_in[0];
    const float* dxyz   = (const float*)d_in[1];
    const float* Wmix   = (const float*)d_in[2];
    const float* bmix   = (const float*)d_in[3];
    const float* Wmean  = (const float*)d_in[4];
    const float* bmean  = (const float*)d_in[5];
    const float* Wscale = (const float*)d_in[6];
    const float* bscale = (const float*)d_in[7];

    float* out  = (float*)d_out;
    float* Lout = out + (size_t)BB * PP;          // second tuple output

    float* par     = (float*)d_ws;                 // 50 * B floats  (819 KB)
    float* ws_part = par + 50 * BB;                // KSPL * 48 * B floats (3.1 MB)

    gemm_kernel<<<dim3(BB / RPB, KSPL), 256, 0, stream>>>(rep, Wmix, Wmean, Wscale, ws_part);

    epilogue_kernel<<<BB / 256, 256, 0, stream>>>(ws_part, bmix, bmean, bscale, Lout, par);

    eval_kernel<<<dim3(BB / 256, PP / PTS_PER_THREAD), 256, 0, stream>>>(dxyz, par, out);
}

// Round 3
// 53.235 us; speedup vs baseline: 1.6271x; 1.2487x over previous
//
#include <hip/hip_runtime.h>
#include <math.h>

#define BB 4096
#define DD 1024
#define KK 5
#define PP 1323
#define PTS_PER_THREAD 21   // 1323 = 63 * 21

// (2*pi)^(-3/2)
#define INV_2PI_POW15 0.06349363593424097f

// ---- head GEMM (MFMA, split-bf16) config ----
#define GR 64        // rows per block
#define GKC 128      // k per staged chunk
#define NCHUNK 2     // chunks per block -> 256 k per block
#define KSPL 4       // k-split blocks (grid.y)
#define NC 48        // padded output cols (47 real)
#define AST 136      // LDS row stride in bf16 elems (128 + 8 pad)

typedef short  bf16x8 __attribute__((ext_vector_type(8)));
typedef short  bf16x4 __attribute__((ext_vector_type(4)));
typedef float  f32x4  __attribute__((ext_vector_type(4)));

__device__ __forceinline__ short f2bf(float f) {
    union { float f; unsigned u; } x; x.f = f;
    const unsigned r = x.u + 0x7fffu + ((x.u >> 16) & 1u);  // RNE
    return (short)(r >> 16);
}
__device__ __forceinline__ float bf2f(short s) {
    union { unsigned u; float f; } x; x.u = ((unsigned)(unsigned short)s) << 16;
    return x.f;
}
__device__ __forceinline__ float softplus_f(float x) {
    return (x > 20.f) ? x : log1pf(expf(x));
}

// ---------------------------------------------------------------------------
// Kernel 0: pack the three weight matrices into bf16 hi/lo, layout [48][1024]
// (n-major so B-fragment reads are 16B contiguous per lane).
// ---------------------------------------------------------------------------
__global__ __launch_bounds__(256) void pack_kernel(
    const float* __restrict__ Wmix,
    const float* __restrict__ Wmean,
    const float* __restrict__ Wscale,
    short* __restrict__ Wh, short* __restrict__ Wl)
{
    const int e = blockIdx.x * 256 + threadIdx.x;   // 0 .. 49151
    const int n = e >> 10;
    const int k = e & 1023;
    float v;
    if (n < 5)       v = Wmix[k * 5 + n];
    else if (n < 17) v = Wmean[k * 12 + (n - 5)];
    else if (n < 47) v = Wscale[k * 30 + (n - 17)];
    else             v = 0.f;
    const short h = f2bf(v);
    Wh[e] = h;
    Wl[e] = f2bf(v - bf2f(h));
}

// ---------------------------------------------------------------------------
// Kernel 1: head GEMM via MFMA.  partial[kz][b][j] = rep[b][k-range] @ W[.][j]
// Grid (64 row-tiles, 4 k-splits) x 256 threads (4 waves).
// Wave w owns rows [b0 + 16w, +16) x all 48 cols. Split-bf16: 3 MFMAs/tile.
// ---------------------------------------------------------------------------
__global__ __launch_bounds__(256) void gemm_kernel(
    const float* __restrict__ rep,
    const short* __restrict__ Wh,
    const short* __restrict__ Wl,
    float* __restrict__ ws_part)
{
    __shared__ short s_hi[GR][AST];
    __shared__ short s_lo[GR][AST];

    const int t  = threadIdx.x;
    const int w  = t >> 6;
    const int l  = t & 63;
    const int lm = l & 15;          // A-row / B-col / C-col within 16-tile
    const int lk = (l >> 4) * 8;    // k offset within 32
    const int b0 = blockIdx.x * GR;
    const int k0 = blockIdx.y * (GKC * NCHUNK);

    f32x4 acc[3] = {f32x4{0,0,0,0}, f32x4{0,0,0,0}, f32x4{0,0,0,0}};

    for (int c = 0; c < NCHUNK; ++c) {
        const int kc = k0 + c * GKC;

        // stage rep tile 64 rows x 128 k, f32 -> bf16 hi/lo (coalesced float4)
#pragma unroll
        for (int i = 0; i < 8; ++i) {
            const int s   = i * 256 + t;
            const int row = s >> 5;          // 32 float4 per row
            const int c4  = s & 31;
            const float4 v = *(const float4*)(rep + (size_t)(b0 + row) * DD + kc + c4 * 4);
            const float f[4] = { v.x, v.y, v.z, v.w };
            bf16x4 h, lo;
#pragma unroll
            for (int u = 0; u < 4; ++u) {
                const short hb = f2bf(f[u]);
                h[u]  = hb;
                lo[u] = f2bf(f[u] - bf2f(hb));
            }
            *(bf16x4*)(&s_hi[row][c4 * 4]) = h;
            *(bf16x4*)(&s_lo[row][c4 * 4]) = lo;
        }
        __syncthreads();

        // B fragments (L2-resident packed weights), [nt][kt]
        bf16x8 bh[3][4], bl[3][4];
#pragma unroll
        for (int nt = 0; nt < 3; ++nt) {
            const size_t nbase = (size_t)(nt * 16 + lm) * DD + kc + lk;
#pragma unroll
            for (int kt = 0; kt < 4; ++kt) {
                bh[nt][kt] = *(const bf16x8*)(Wh + nbase + kt * 32);
                bl[nt][kt] = *(const bf16x8*)(Wl + nbase + kt * 32);
            }
        }

        const int arow = w * 16 + lm;
#pragma unroll
        for (int kt = 0; kt < 4; ++kt) {
            const bf16x8 ah = *(const bf16x8*)(&s_hi[arow][kt * 32 + lk]);
            const bf16x8 al = *(const bf16x8*)(&s_lo[arow][kt * 32 + lk]);
#pragma unroll
            for (int nt = 0; nt < 3; ++nt) {
                acc[nt] = __builtin_amdgcn_mfma_f32_16x16x32_bf16(ah, bh[nt][kt], acc[nt], 0, 0, 0);
                acc[nt] = __builtin_amdgcn_mfma_f32_16x16x32_bf16(ah, bl[nt][kt], acc[nt], 0, 0, 0);
                acc[nt] = __builtin_amdgcn_mfma_f32_16x16x32_bf16(al, bh[nt][kt], acc[nt], 0, 0, 0);
            }
        }
        __syncthreads();
    }

    // C layout: col = lane&15, row = (lane>>4)*4 + reg   [m89]
    // store partials: ws_part[(kz*BB + b)*48 + j]  (64B-coalesced per lane group)
    const int bbase = b0 + w * 16 + (l >> 4) * 4;
#pragma unroll
    for (int nt = 0; nt < 3; ++nt) {
        const int j = nt * 16 + lm;
#pragma unroll
        for (int r = 0; r < 4; ++r) {
            ws_part[((size_t)blockIdx.y * BB + bbase + r) * NC + j] = acc[nt][r];
        }
    }
}

// ---------------------------------------------------------------------------
// Kernel 2: epilogue. One thread per batch row: sum k-split partials, add
// biases, softmax, softplus Cholesky, write L and SoA params.
// ---------------------------------------------------------------------------
__global__ __launch_bounds__(256) void epilogue_kernel(
    const float* __restrict__ ws_part,
    const float* __restrict__ bmix,
    const float* __restrict__ bmean,
    const float* __restrict__ bscale,
    float* __restrict__ Lout,
    float* __restrict__ par)
{
    const int b = blockIdx.x * 256 + threadIdx.x;

    float v[NC];
#pragma unroll
    for (int j4 = 0; j4 < NC / 4; ++j4) {
        f32x4 s = {0.f, 0.f, 0.f, 0.f};
#pragma unroll
        for (int kz = 0; kz < KSPL; ++kz)
            s += *(const f32x4*)(ws_part + ((size_t)kz * BB + b) * NC + j4 * 4);
#pragma unroll
        for (int u = 0; u < 4; ++u) v[j4 * 4 + u] = s[u];
    }

    // softmax over 5 logits
    float logits[KK];
#pragma unroll
    for (int k = 0; k < KK; ++k) logits[k] = v[k] + bmix[k];
    float mx = logits[0];
#pragma unroll
    for (int k = 1; k < KK; ++k) mx = fmaxf(mx, logits[k]);
    float e[KK]; float s = 0.f;
#pragma unroll
    for (int k = 0; k < KK; ++k) { e[k] = expf(logits[k] - mx); s += e[k]; }
    const float inv_s = 1.f / s;

    float means[12];
#pragma unroll
    for (int j = 0; j < 12; ++j) means[j] = v[5 + j] + bmean[j];

#pragma unroll
    for (int k = 0; k < KK; ++k) {
        const float s0 = v[17 + k * 6 + 0] + bscale[k * 6 + 0];
        const float s1 = v[17 + k * 6 + 1] + bscale[k * 6 + 1];
        const float s2 = v[17 + k * 6 + 2] + bscale[k * 6 + 2];
        const float s3 = v[17 + k * 6 + 3] + bscale[k * 6 + 3];
        const float s4 = v[17 + k * 6 + 4] + bscale[k * 6 + 4];
        const float s5 = v[17 + k * 6 + 5] + bscale[k * 6 + 5];

        const float L00 = softplus_f(s0);
        const float L10 = s1;
        const float L11 = softplus_f(s2);
        const float L20 = s3;
        const float L21 = s4;
        const float L22 = softplus_f(s5);

        const float m0 = (k == 0) ? 0.f : means[(k - 1) * 3 + 0];
        const float m1 = (k == 0) ? 0.f : means[(k - 1) * 3 + 1];
        const float m2 = (k == 0) ? 0.f : means[(k - 1) * 3 + 2];

        const float r00 = 1.f / L00;
        const float r11 = 1.f / L11;
        const float r22 = 1.f / L22;
        const float wgt = e[k] * inv_s;
        const float a   = wgt * r00 * r11 * r22 * INV_2PI_POW15;

        float* Lo = Lout + ((size_t)b * KK + k) * 9;
        Lo[0] = L00; Lo[1] = 0.f; Lo[2] = 0.f;
        Lo[3] = L10; Lo[4] = L11; Lo[5] = 0.f;
        Lo[6] = L20; Lo[7] = L21; Lo[8] = L22;

        const int pj = k * 10;
        par[(pj + 0) * BB + b] = m0;
        par[(pj + 1) * BB + b] = m1;
        par[(pj + 2) * BB + b] = m2;
        par[(pj + 3) * BB + b] = r00;
        par[(pj + 4) * BB + b] = L10;
        par[(pj + 5) * BB + b] = r11;
        par[(pj + 6) * BB + b] = L20;
        par[(pj + 7) * BB + b] = L21;
        par[(pj + 8) * BB + b] = r22;
        par[(pj + 9) * BB + b] = a;
    }
}

// ---------------------------------------------------------------------------
// Kernel 3: per-(p,b) mixture density (memory-bound, at HBM floor).
// out[p*B + b] = sum_k a_k * exp(-0.5 * |L^-1 (x - mu)|^2)
// ---------------------------------------------------------------------------
__global__ __launch_bounds__(256) void eval_kernel(
    const float* __restrict__ dxyz,
    const float* __restrict__ par,
    float* __restrict__ out)
{
    const int b = blockIdx.x * 256 + threadIdx.x;

    float m0[KK], m1[KK], m2[KK], r00[KK], l10[KK], r11[KK], l20[KK], l21[KK], r22[KK], am[KK];
#pragma unroll
    for (int k = 0; k < KK; ++k) {
        const int pj = k * 10;
        m0[k]  = par[(pj + 0) * BB + b];
        m1[k]  = par[(pj + 1) * BB + b];
        m2[k]  = par[(pj + 2) * BB + b];
        r00[k] = par[(pj + 3) * BB + b];
        l10[k] = par[(pj + 4) * BB + b];
        r11[k] = par[(pj + 5) * BB + b];
        l20[k] = par[(pj + 6) * BB + b];
        l21[k] = par[(pj + 7) * BB + b];
        r22[k] = par[(pj + 8) * BB + b];
        am[k]  = par[(pj + 9) * BB + b];
    }

    const int p0 = blockIdx.y * PTS_PER_THREAD;
#pragma unroll 3
    for (int i = 0; i < PTS_PER_THREAD; ++i) {
        const int p = p0 + i;
        const size_t idx = (size_t)p * BB + b;
        const float* xv = dxyz + idx * 3;
        const float x0 = xv[0];
        const float x1 = xv[1];
        const float x2 = xv[2];

        float res = 0.f;
#pragma unroll
        for (int k = 0; k < KK; ++k) {
            const float d0 = x0 - m0[k];
            const float d1 = x1 - m1[k];
            const float d2 = x2 - m2[k];
            const float z0 = d0 * r00[k];
            const float z1 = fmaf(-l10[k], z0, d1) * r11[k];
            const float z2 = fmaf(-l21[k], z1, fmaf(-l20[k], z0, d2)) * r22[k];
            const float q  = fmaf(z2, z2, fmaf(z1, z1, z0 * z0));
            res = fmaf(am[k], __expf(-0.5f * q), res);
        }
        out[idx] = res;
    }
}

extern "C" void kernel_launch(void* const* d_in, const int* in_sizes, int n_in,
                              void* d_out, int out_size, void* d_ws, size_t ws_size,
                              hipStream_t stream) {
    const float* rep    = (const float*)d_in[0];
    const float* dxyz   = (const float*)d_in[1];
    const float* Wmix   = (const float*)d_in[2];
    const float* bmix   = (const float*)d_in[3];
    const float* Wmean  = (const float*)d_in[4];
    const float* bmean  = (const float*)d_in[5];
    const float* Wscale = (const float*)d_in[6];
    const float* bscale = (const float*)d_in[7];

    float* out  = (float*)d_out;
    float* Lout = out + (size_t)BB * PP;          // second tuple output

    float* par     = (float*)d_ws;                           // 50*B f32      (819 KB)
    float* ws_part = par + 50 * BB;                          // 4*B*48 f32    (3.15 MB)
    short* Wh      = (short*)(ws_part + (size_t)KSPL * BB * NC);  // 48*1024 bf16 (98 KB)
    short* Wl      = Wh + 48 * DD;                                // 48*1024 bf16 (98 KB)

    pack_kernel<<<192, 256, 0, stream>>>(Wmix, Wmean, Wscale, Wh, Wl);

    gemm_kernel<<<dim3(BB / GR, KSPL), 256, 0, stream>>>(rep, Wh, Wl, ws_part);

    epilogue_kernel<<<BB / 256, 256, 0, stream>>>(ws_part, bmix, bmean, bscale, Lout, par);

    eval_kernel<<<dim3(BB / 256, PP / PTS_PER_THREAD), 256, 0, stream>>>(dxyz, par, out);
}

// Round 4
// 46.186 us; speedup vs baseline: 1.8754x; 1.1526x over previous
//
#include <hip/hip_runtime.h>
#include <math.h>

#define BB 4096
#define DD 1024
#define KK 5
#define PP 1323
#define PTS_PER_THREAD 21   // 1323 = 63 * 21

// (2*pi)^(-3/2)
#define INV_2PI_POW15 0.06349363593424097f

// ---- fused head GEMM config ----
#define GR 16         // rows per block -> 256 blocks (1/CU)
#define NC 48         // padded output cols (47 real)
#define AST 1026      // LDS row stride in bf16 elems (1024 + 2: odd word stride)
#define CST 53        // C tile stride (odd)

typedef short  bf16x8 __attribute__((ext_vector_type(8)));
typedef short  bf16x4 __attribute__((ext_vector_type(4)));
typedef float  f32x4  __attribute__((ext_vector_type(4)));

__device__ __forceinline__ short f2bf(float f) {
    union { float f; unsigned u; } x; x.f = f;
    const unsigned r = x.u + 0x7fffu + ((x.u >> 16) & 1u);  // RNE
    return (short)(r >> 16);
}
__device__ __forceinline__ float bf2f(short s) {
    union { unsigned u; float f; } x; x.u = ((unsigned)(unsigned short)s) << 16;
    return x.f;
}
__device__ __forceinline__ float softplus_f(float x) {
    return (x > 20.f) ? x : log1pf(expf(x));
}

// ---------------------------------------------------------------------------
// Kernel 0: pack the three weight matrices into bf16 hi/lo, layout [48][1024]
// ---------------------------------------------------------------------------
__global__ __launch_bounds__(256) void pack_kernel(
    const float* __restrict__ Wmix,
    const float* __restrict__ Wmean,
    const float* __restrict__ Wscale,
    short* __restrict__ Wh, short* __restrict__ Wl)
{
    const int e = blockIdx.x * 256 + threadIdx.x;   // 0 .. 49151
    const int n = e >> 10;
    const int k = e & 1023;
    float v;
    if (n < 5)       v = Wmix[k * 5 + n];
    else if (n < 17) v = Wmean[k * 12 + (n - 5)];
    else if (n < 47) v = Wscale[k * 30 + (n - 17)];
    else             v = 0.f;
    const short h = f2bf(v);
    Wh[e] = h;
    Wl[e] = f2bf(v - bf2f(h));
}

// ---------------------------------------------------------------------------
// Kernel 1: fused head. 256 blocks x 16 rows. Full K=1024 per block
// (4 waves = 4 k-quarters, LDS cross-wave reduce), then per-row
// softmax/softplus/Cholesky tail in lanes 0..15 of wave 0.
// Split-bf16 MFMA: rep = hi + lo, 3 MFMAs per (kt,nt).
// ---------------------------------------------------------------------------
__global__ __launch_bounds__(256) void head_fused_kernel(
    const float* __restrict__ rep,
    const short* __restrict__ Wh,
    const short* __restrict__ Wl,
    const float* __restrict__ bmix,
    const float* __restrict__ bmean,
    const float* __restrict__ bscale,
    float* __restrict__ Lout,
    float* __restrict__ par)
{
    __shared__ short s_hi[GR][AST];
    __shared__ short s_lo[GR][AST];
    __shared__ float s_red[3][64][12];
    __shared__ float s_c[GR][CST];

    const int t  = threadIdx.x;
    const int w  = t >> 6;          // wave id = k-quarter
    const int l  = t & 63;
    const int lm = l & 15;          // A-row / B-col / C-col within 16
    const int lk = (l >> 4) * 8;    // k offset within 32
    const int b0 = blockIdx.x * GR;

    // ---- stage rep tile 16 rows x 1024 k, f32 -> bf16 hi/lo ----
    // 16384 f32 / 256 threads = 16 float4 per thread, all in flight.
#pragma unroll
    for (int i = 0; i < 16; ++i) {
        const int s   = i * 256 + t;
        const int row = s >> 8;          // 256 float4 per row
        const int c4  = s & 255;
        const float4 v = *(const float4*)(rep + (size_t)(b0 + row) * DD + c4 * 4);
        const float f[4] = { v.x, v.y, v.z, v.w };
        bf16x4 h, lo;
#pragma unroll
        for (int u = 0; u < 4; ++u) {
            const short hb = f2bf(f[u]);
            h[u]  = hb;
            lo[u] = f2bf(f[u] - bf2f(hb));
        }
        *(bf16x4*)(&s_hi[row][c4 * 4]) = h;
        *(bf16x4*)(&s_lo[row][c4 * 4]) = lo;
    }
    __syncthreads();

    // ---- MFMA over this wave's k-quarter ----
    f32x4 acc[3] = {f32x4{0,0,0,0}, f32x4{0,0,0,0}, f32x4{0,0,0,0}};
    const int kq0 = w * 256;

#pragma unroll
    for (int kt = 0; kt < 8; ++kt) {
        const int kof = kq0 + kt * 32 + lk;
        const bf16x8 ah = *(const bf16x8*)(&s_hi[lm][kof]);
        const bf16x8 al = *(const bf16x8*)(&s_lo[lm][kof]);
#pragma unroll
        for (int nt = 0; nt < 3; ++nt) {
            const size_t wb = (size_t)(nt * 16 + lm) * DD + kof;
            const bf16x8 bh = *(const bf16x8*)(Wh + wb);
            const bf16x8 bl = *(const bf16x8*)(Wl + wb);
            acc[nt] = __builtin_amdgcn_mfma_f32_16x16x32_bf16(ah, bh, acc[nt], 0, 0, 0);
            acc[nt] = __builtin_amdgcn_mfma_f32_16x16x32_bf16(ah, bl, acc[nt], 0, 0, 0);
            acc[nt] = __builtin_amdgcn_mfma_f32_16x16x32_bf16(al, bh, acc[nt], 0, 0, 0);
        }
    }

    // ---- cross-wave k reduction ----
    if (w > 0) {
#pragma unroll
        for (int nt = 0; nt < 3; ++nt)
#pragma unroll
            for (int r = 0; r < 4; ++r)
                s_red[w - 1][l][nt * 4 + r] = acc[nt][r];
    }
    __syncthreads();
    if (w == 0) {
#pragma unroll
        for (int q = 0; q < 3; ++q)
#pragma unroll
            for (int nt = 0; nt < 3; ++nt)
#pragma unroll
                for (int r = 0; r < 4; ++r)
                    acc[nt][r] += s_red[q][l][nt * 4 + r];
        // C layout: col = lane&15, row = (lane>>4)*4 + reg   [m89]
#pragma unroll
        for (int nt = 0; nt < 3; ++nt)
#pragma unroll
            for (int r = 0; r < 4; ++r)
                s_c[(l >> 4) * 4 + r][nt * 16 + lm] = acc[nt][r];
    }
    __syncthreads();

    // ---- per-row tail: lanes 0..15 of wave 0 ----
    if (t < GR) {
        const int b = b0 + t;
        float v[47];
#pragma unroll
        for (int j = 0; j < 47; ++j) v[j] = s_c[t][j];

        // softmax over 5 logits
        float logits[KK];
#pragma unroll
        for (int k = 0; k < KK; ++k) logits[k] = v[k] + bmix[k];
        float mx = logits[0];
#pragma unroll
        for (int k = 1; k < KK; ++k) mx = fmaxf(mx, logits[k]);
        float e[KK]; float s = 0.f;
#pragma unroll
        for (int k = 0; k < KK; ++k) { e[k] = expf(logits[k] - mx); s += e[k]; }
        const float inv_s = 1.f / s;

        float means[12];
#pragma unroll
        for (int j = 0; j < 12; ++j) means[j] = v[5 + j] + bmean[j];

#pragma unroll
        for (int k = 0; k < KK; ++k) {
            const float s0 = v[17 + k * 6 + 0] + bscale[k * 6 + 0];
            const float s1 = v[17 + k * 6 + 1] + bscale[k * 6 + 1];
            const float s2 = v[17 + k * 6 + 2] + bscale[k * 6 + 2];
            const float s3 = v[17 + k * 6 + 3] + bscale[k * 6 + 3];
            const float s4 = v[17 + k * 6 + 4] + bscale[k * 6 + 4];
            const float s5 = v[17 + k * 6 + 5] + bscale[k * 6 + 5];

            const float L00 = softplus_f(s0);
            const float L10 = s1;
            const float L11 = softplus_f(s2);
            const float L20 = s3;
            const float L21 = s4;
            const float L22 = softplus_f(s5);

            const float m0 = (k == 0) ? 0.f : means[(k - 1) * 3 + 0];
            const float m1 = (k == 0) ? 0.f : means[(k - 1) * 3 + 1];
            const float m2 = (k == 0) ? 0.f : means[(k - 1) * 3 + 2];

            const float r00 = 1.f / L00;
            const float r11 = 1.f / L11;
            const float r22 = 1.f / L22;
            const float wgt = e[k] * inv_s;
            const float a   = wgt * r00 * r11 * r22 * INV_2PI_POW15;

            float* Lo = Lout + ((size_t)b * KK + k) * 9;
            Lo[0] = L00; Lo[1] = 0.f; Lo[2] = 0.f;
            Lo[3] = L10; Lo[4] = L11; Lo[5] = 0.f;
            Lo[6] = L20; Lo[7] = L21; Lo[8] = L22;

            const int pj = k * 10;
            par[(pj + 0) * BB + b] = m0;
            par[(pj + 1) * BB + b] = m1;
            par[(pj + 2) * BB + b] = m2;
            par[(pj + 3) * BB + b] = r00;
            par[(pj + 4) * BB + b] = L10;
            par[(pj + 5) * BB + b] = r11;
            par[(pj + 6) * BB + b] = L20;
            par[(pj + 7) * BB + b] = L21;
            par[(pj + 8) * BB + b] = r22;
            par[(pj + 9) * BB + b] = a;
        }
    }
}

// ---------------------------------------------------------------------------
// Kernel 2: per-(p,b) mixture density (memory-bound, at HBM floor).
// out[p*B + b] = sum_k a_k * exp(-0.5 * |L^-1 (x - mu)|^2)
// ---------------------------------------------------------------------------
__global__ __launch_bounds__(256) void eval_kernel(
    const float* __restrict__ dxyz,
    const float* __restrict__ par,
    float* __restrict__ out)
{
    const int b = blockIdx.x * 256 + threadIdx.x;

    float m0[KK], m1[KK], m2[KK], r00[KK], l10[KK], r11[KK], l20[KK], l21[KK], r22[KK], am[KK];
#pragma unroll
    for (int k = 0; k < KK; ++k) {
        const int pj = k * 10;
        m0[k]  = par[(pj + 0) * BB + b];
        m1[k]  = par[(pj + 1) * BB + b];
        m2[k]  = par[(pj + 2) * BB + b];
        r00[k] = par[(pj + 3) * BB + b];
        l10[k] = par[(pj + 4) * BB + b];
        r11[k] = par[(pj + 5) * BB + b];
        l20[k] = par[(pj + 6) * BB + b];
        l21[k] = par[(pj + 7) * BB + b];
        r22[k] = par[(pj + 8) * BB + b];
        am[k]  = par[(pj + 9) * BB + b];
    }

    const int p0 = blockIdx.y * PTS_PER_THREAD;
#pragma unroll 3
    for (int i = 0; i < PTS_PER_THREAD; ++i) {
        const int p = p0 + i;
        const size_t idx = (size_t)p * BB + b;
        const float* xv = dxyz + idx * 3;
        const float x0 = xv[0];
        const float x1 = xv[1];
        const float x2 = xv[2];

        float res = 0.f;
#pragma unroll
        for (int k = 0; k < KK; ++k) {
            const float d0 = x0 - m0[k];
            const float d1 = x1 - m1[k];
            const float d2 = x2 - m2[k];
            const float z0 = d0 * r00[k];
            const float z1 = fmaf(-l10[k], z0, d1) * r11[k];
            const float z2 = fmaf(-l21[k], z1, fmaf(-l20[k], z0, d2)) * r22[k];
            const float q  = fmaf(z2, z2, fmaf(z1, z1, z0 * z0));
            res = fmaf(am[k], __expf(-0.5f * q), res);
        }
        out[idx] = res;
    }
}

extern "C" void kernel_launch(void* const* d_in, const int* in_sizes, int n_in,
                              void* d_out, int out_size, void* d_ws, size_t ws_size,
                              hipStream_t stream) {
    const float* rep    = (const float*)d_in[0];
    const float* dxyz   = (const float*)d_in[1];
    const float* Wmix   = (const float*)d_in[2];
    const float* bmix   = (const float*)d_in[3];
    const float* Wmean  = (const float*)d_in[4];
    const float* bmean  = (const float*)d_in[5];
    const float* Wscale = (const float*)d_in[6];
    const float* bscale = (const float*)d_in[7];

    float* out  = (float*)d_out;
    float* Lout = out + (size_t)BB * PP;          // second tuple output

    float* par = (float*)d_ws;                    // 50*B f32 (819 KB)
    short* Wh  = (short*)(par + 50 * BB);         // 48*1024 bf16 (98 KB)
    short* Wl  = Wh + 48 * DD;                    // 48*1024 bf16 (98 KB)

    pack_kernel<<<192, 256, 0, stream>>>(Wmix, Wmean, Wscale, Wh, Wl);

    head_fused_kernel<<<BB / GR, 256, 0, stream>>>(rep, Wh, Wl, bmix, bmean, bscale, Lout, par);

    eval_kernel<<<dim3(BB / 256, PP / PTS_PER_THREAD), 256, 0, stream>>>(dxyz, par, out);
}